// Round 10
// baseline (106.668 us; speedup 1.0000x reference)
//
#include <hip/hip_runtime.h>
#include <math.h>

#define NNODES 20000
#define NEDGES 320000
#define CDIM   256
#define NC     200
#define NB     2048                 // lerp intervals; Wt rows alloc'd 2112 (66*32)
#define TROWS  2112
#define DRANGE 24.0f
#define DELTA  (DRANGE / (float)NB)
#define INVDEL ((float)NB / DRANGE)
#define NTHR   256
#define GTHR   512                  // gathernode block size (8 waves)
#define RS     264                  // LDS row stride in ushorts (528B)
#define CAP    48                   // bucket capacity per node (Poisson(16); P(deg>=48)~1e-11)
#define XNR    32                   // rows per xw3/table tile
#define GNR    16                   // rows per fused gather+node tile

#define FILLB  ((NEDGES + NTHR - 1) / NTHR)   // 1250
#define PACKB  1248
#define ZEROB  20
#define TBLK2  (TROWS / 32)                   // 66
#define XW3B   (NNODES / XNR)                 // 625
#define GNB    (NNODES / GNR)                 // 1250

typedef __attribute__((ext_vector_type(8))) short bf16x8;
typedef __attribute__((ext_vector_type(4))) float f32x4;
typedef __attribute__((ext_vector_type(8))) unsigned short u16x8;

__device__ __forceinline__ unsigned short f2bf(float f) {
    unsigned int u = __float_as_uint(f);
    unsigned int r = (u + 0x7FFFu + ((u >> 16) & 1u)) >> 16;   // RNE
    return (unsigned short)r;
}
__device__ __forceinline__ float bf2f(unsigned short h) {
    return __uint_as_float(((unsigned int)h) << 16);
}
__device__ __forceinline__ float ssp_f(float x) {
    const float LOG2V = 0.6931471805599453f;
    if (x < 14.0f) return __logf(1.0f + __expf(x)) - LOG2V;
    return x - LOG2V;
}

// ---------- pack weights + zero cnt (one small kernel) ----------
__global__ __launch_bounds__(NTHR)
void packzero_kernel(const float* __restrict__ w3, const float* __restrict__ w4,
                     const float* __restrict__ w5, const float* __restrict__ w1,
                     const float* __restrict__ w2,
                     unsigned short* __restrict__ w3p, unsigned short* __restrict__ w4p,
                     unsigned short* __restrict__ w5p, unsigned short* __restrict__ w1p,
                     unsigned short* __restrict__ w2p,
                     int4* __restrict__ cnt4)
{
    if (blockIdx.x < PACKB) {
        int idx = blockIdx.x * NTHR + threadIdx.x;             // 0 .. 319487
        if (idx < 196608) {
            int m = idx >> 16;
            int r = idx & 65535;
            int j = r & 7, c = (r >> 3) & 255, lg = (r >> 11) & 3, kt = r >> 13;
            int k = kt * 32 + lg * 8 + j;
            const float* w = (m == 0) ? w3 : (m == 1) ? w4 : w5;
            unsigned short* wp = (m == 0) ? w3p : (m == 1) ? w4p : w5p;
            wp[r] = f2bf(w[k * CDIM + c]);
        } else if (idx < 253952) {
            int r = idx - 196608;                        // w1p: 224*256 = 57344
            int j = r & 7, c = (r >> 3) & 255, lg = (r >> 11) & 3, kt = r >> 13;
            int k = kt * 32 + lg * 8 + j;
            w1p[r] = (k < NC) ? f2bf(w1[k * CDIM + c]) : (unsigned short)0;
        } else {
            int r = idx - 253952;                        // w2p: 65536
            int j = r & 7, c = (r >> 3) & 255, lg = (r >> 11) & 3, kt = r >> 13;
            int k = kt * 32 + lg * 8 + j;
            w2p[r] = f2bf(w2[k * CDIM + c]);
        }
    } else {
        int i = (blockIdx.x - PACKB) * NTHR + threadIdx.x;
        if (i < NNODES / 4) cnt4[i] = make_int4(0, 0, 0, 0);
    }
}

// ---------- mega kernel: table (32-bin) + xw3 (32-row) + fill, co-resident ----------
// Table output INTERLEAVED: Wtbi[i][c][0..1] = {w[i], w[i+1]}.
__global__ __launch_bounds__(NTHR, 4)
void mega_kernel(const unsigned short* __restrict__ w1p, const float* __restrict__ b1,
                 const unsigned short* __restrict__ w2p, const float* __restrict__ b2,
                 unsigned short* __restrict__ Wtbi,
                 const float* __restrict__ x,
                 const unsigned short* __restrict__ w3p,
                 unsigned short* __restrict__ xw3h,
                 const float* __restrict__ pos,
                 const int* __restrict__ snd,
                 const int* __restrict__ rcv,
                 int* __restrict__ cnt,
                 int2* __restrict__ slots)
{
    __shared__ unsigned short s_a[XNR * RS];     // 16896 B
    const int t = threadIdx.x;

    if (blockIdx.x < TBLK2) {
        // ----- filter table, 32 bins per block -----
        const int m0 = blockIdx.x * 32;
        const float cstep = 20.0f / 199.0f;

        {
            int row = t >> 3;
            int k0 = (t & 7) * 28;
            float d = (float)(m0 + row) * DELTA;
            #pragma unroll
            for (int j = 0; j < 28; ++j) {
                int k = k0 + j;
                float dd = d - (float)k * cstep;
                float v = (k < NC) ? __expf(-10.0f * dd * dd) : 0.0f;
                s_a[row * RS + k] = f2bf(v);
            }
        }
        __syncthreads();

        const int l = t & 63, w = t >> 6, lr = l & 15, lg = l >> 4, nb = w * 64;
        f32x4 acc[2][4];
        #pragma unroll
        for (int mt = 0; mt < 2; ++mt)
            #pragma unroll
            for (int nt = 0; nt < 4; ++nt) acc[mt][nt] = (f32x4)0.0f;

        // GEMM1: K = 224
        #pragma unroll 2
        for (int kt = 0; kt < 7; ++kt) {
            bf16x8 a[2];
            #pragma unroll
            for (int mt = 0; mt < 2; ++mt)
                a[mt] = *(const bf16x8*)&s_a[(mt * 16 + lr) * RS + kt * 32 + lg * 8];
            #pragma unroll
            for (int nt = 0; nt < 4; ++nt) {
                bf16x8 b = *(const bf16x8*)&w1p[(size_t)(((kt * 4 + lg) * 256) + nb + nt * 16 + lr) * 8];
                #pragma unroll
                for (int mt = 0; mt < 2; ++mt)
                    acc[mt][nt] = __builtin_amdgcn_mfma_f32_16x16x32_bf16(a[mt], b, acc[mt][nt], 0, 0, 0);
            }
        }
        __syncthreads();

        #pragma unroll
        for (int nt = 0; nt < 4; ++nt) {
            int col = nb + nt * 16 + lr;
            float bias = b1[col];
            #pragma unroll
            for (int mt = 0; mt < 2; ++mt)
                #pragma unroll
                for (int rr = 0; rr < 4; ++rr)
                    s_a[(mt * 16 + lg * 4 + rr) * RS + col] = f2bf(ssp_f(acc[mt][nt][rr] + bias));
        }
        __syncthreads();

        #pragma unroll
        for (int mt = 0; mt < 2; ++mt)
            #pragma unroll
            for (int nt = 0; nt < 4; ++nt) acc[mt][nt] = (f32x4)0.0f;

        // GEMM2: K = 256
        #pragma unroll 2
        for (int kt = 0; kt < 8; ++kt) {
            bf16x8 a[2];
            #pragma unroll
            for (int mt = 0; mt < 2; ++mt)
                a[mt] = *(const bf16x8*)&s_a[(mt * 16 + lr) * RS + kt * 32 + lg * 8];
            #pragma unroll
            for (int nt = 0; nt < 4; ++nt) {
                bf16x8 b = *(const bf16x8*)&w2p[(size_t)(((kt * 4 + lg) * 256) + nb + nt * 16 + lr) * 8];
                #pragma unroll
                for (int mt = 0; mt < 2; ++mt)
                    acc[mt][nt] = __builtin_amdgcn_mfma_f32_16x16x32_bf16(a[mt], b, acc[mt][nt], 0, 0, 0);
            }
        }

        #pragma unroll
        for (int nt = 0; nt < 4; ++nt) {
            int col = nb + nt * 16 + lr;
            float bias = b2[col];
            #pragma unroll
            for (int mt = 0; mt < 2; ++mt)
                #pragma unroll
                for (int rr = 0; rr < 4; ++rr) {
                    int row = m0 + mt * 16 + lg * 4 + rr;
                    unsigned short v = f2bf(ssp_f(acc[mt][nt][rr] + bias));
                    Wtbi[(size_t)row * 512 + col * 2] = v;                   // slot 0 of row
                    if (row > 0)
                        Wtbi[(size_t)(row - 1) * 512 + col * 2 + 1] = v;     // slot 1 of row-1
                }
        }
    } else if (blockIdx.x < TBLK2 + XW3B) {
        // ----- xw3 = x @ w3, 32 rows per block -----
        const int m0 = (blockIdx.x - TBLK2) * XNR;

        {
            int row = t >> 3;
            const float* src = &x[(size_t)(m0 + row) * CDIM];
            unsigned short* dst = &s_a[row * RS];
            #pragma unroll
            for (int oc = 0; oc < 4; ++oc) {
                int c0 = oc * 64 + (t & 7) * 8;
                float4 a = *(const float4*)&src[c0];
                float4 b = *(const float4*)&src[c0 + 4];
                u16x8 v;
                v[0] = f2bf(a.x); v[1] = f2bf(a.y); v[2] = f2bf(a.z); v[3] = f2bf(a.w);
                v[4] = f2bf(b.x); v[5] = f2bf(b.y); v[6] = f2bf(b.z); v[7] = f2bf(b.w);
                *(u16x8*)&dst[c0] = v;
            }
        }
        __syncthreads();

        const int l = t & 63, w = t >> 6, lr = l & 15, lg = l >> 4, nb = w * 64;
        f32x4 acc[2][4];
        #pragma unroll
        for (int mt = 0; mt < 2; ++mt)
            #pragma unroll
            for (int nt = 0; nt < 4; ++nt) acc[mt][nt] = (f32x4)0.0f;

        #pragma unroll 2
        for (int kt = 0; kt < 8; ++kt) {
            bf16x8 a[2];
            #pragma unroll
            for (int mt = 0; mt < 2; ++mt)
                a[mt] = *(const bf16x8*)&s_a[(mt * 16 + lr) * RS + kt * 32 + lg * 8];
            #pragma unroll
            for (int nt = 0; nt < 4; ++nt) {
                bf16x8 b = *(const bf16x8*)&w3p[(size_t)(((kt * 4 + lg) * 256) + nb + nt * 16 + lr) * 8];
                #pragma unroll
                for (int mt = 0; mt < 2; ++mt)
                    acc[mt][nt] = __builtin_amdgcn_mfma_f32_16x16x32_bf16(a[mt], b, acc[mt][nt], 0, 0, 0);
            }
        }

        #pragma unroll
        for (int nt = 0; nt < 4; ++nt) {
            int col = nb + nt * 16 + lr;
            #pragma unroll
            for (int mt = 0; mt < 2; ++mt)
                #pragma unroll
                for (int rr = 0; rr < 4; ++rr) {
                    int row = m0 + mt * 16 + lg * 4 + rr;
                    xw3h[(size_t)row * CDIM + col] = f2bf(acc[mt][nt][rr]);
                }
        }
    } else {
        // ----- fill: edge bucketing -----
        int e = (blockIdx.x - TBLK2 - XW3B) * NTHR + threadIdx.x;
        if (e >= NEDGES) return;
        int s = snd[e], r = rcv[e];
        float dx = pos[r * 3 + 0] - pos[s * 3 + 0];
        float dy = pos[r * 3 + 1] - pos[s * 3 + 1];
        float dz = pos[r * 3 + 2] - pos[s * 3 + 2];
        float d = sqrtf(dx * dx + dy * dy + dz * dz);
        float u = fminf(d * INVDEL, (float)NB - 0.001f);
        int rank = atomicAdd(&cnt[r], 1);
        if (rank < CAP) {
            int2 v; v.x = s; v.y = __float_as_int(u);
            slots[(size_t)r * CAP + rank] = v;
        }
    }
}

// ---------- fused gather + node MLP: 16 nodes per block, 512 threads (8 waves) -----
// Phase 1 (gather): wave w accumulates conv for rows w*2..w*2+1 (4 ch/lane, one 16B
// interleaved-table load + one 8B feature load per edge), writes bf16 into s_a.
// Tail edges handled as one clamped batch (descriptors clamped to deg-1; FMAs
// guarded by wave-uniform branches) -> no serial-latency tail.
// Phase 2 (MLP): 8 waves split the 256 columns (32 each); out = x + ssp(conv@w4+b4)@w5+b5.
// 1250 blocks x 8 waves = 10000 waves -> occupancy cap ~100% (vs 61% at 4 waves).

#define GDESC4(src) { \
    sD0 = __shfl((src).x, 0); sD1 = __shfl((src).x, 1); \
    sD2 = __shfl((src).x, 2); sD3 = __shfl((src).x, 3); \
    float u0_ = __int_as_float(__shfl((src).y, 0)); iD0 = (int)u0_; fD0 = u0_ - (float)iD0; \
    float u1_ = __int_as_float(__shfl((src).y, 1)); iD1 = (int)u1_; fD1 = u1_ - (float)iD1; \
    float u2_ = __int_as_float(__shfl((src).y, 2)); iD2 = (int)u2_; fD2 = u2_ - (float)iD2; \
    float u3_ = __int_as_float(__shfl((src).y, 3)); iD3 = (int)u3_; fD3 = u3_ - (float)iD3; }

#define GLF(e) { \
    u16x8 wab = *(const u16x8*)&Wtbi[(size_t)iD##e * 512 + c8]; \
    ushort4 fx = *(const ushort4*)&xw3h[(size_t)sD##e * CDIM + c4]; \
    float a0, a1; \
    a0 = bf2f(wab[0]); a1 = bf2f(wab[1]); acc.x = fmaf(fmaf(fD##e, a1 - a0, a0), bf2f(fx.x), acc.x); \
    a0 = bf2f(wab[2]); a1 = bf2f(wab[3]); acc.y = fmaf(fmaf(fD##e, a1 - a0, a0), bf2f(fx.y), acc.y); \
    a0 = bf2f(wab[4]); a1 = bf2f(wab[5]); acc.z = fmaf(fmaf(fD##e, a1 - a0, a0), bf2f(fx.z), acc.z); \
    a0 = bf2f(wab[6]); a1 = bf2f(wab[7]); acc.w = fmaf(fmaf(fD##e, a1 - a0, a0), bf2f(fx.w), acc.w); }

__global__ __launch_bounds__(GTHR, 8)
void gathernode_kernel(const int* __restrict__ cnt,
                       const int2* __restrict__ slots,
                       const unsigned short* __restrict__ Wtbi,
                       const unsigned short* __restrict__ xw3h,
                       const unsigned short* __restrict__ w4p, const float* __restrict__ b4,
                       const unsigned short* __restrict__ w5p, const float* __restrict__ b5,
                       const float* __restrict__ x,
                       float* __restrict__ out)
{
    __shared__ unsigned short s_a[GNR * RS];     // 8448 B
    const int t = threadIdx.x;
    const int w = t >> 6, l = t & 63;            // w: 0..7
    const int c4 = l * 4;          // channel offset (ushorts) in xw3h / s_a rows
    const int c8 = l * 8;          // offset (ushorts) in interleaved Wtbi row
    const int m0 = blockIdx.x * GNR;             // NNODES % 16 == 0 -> no guards

    // ---- phase 1: gather 2 nodes per wave ----
    for (int rr = 0; rr < 2; ++rr) {
        const int row = w * 2 + rr;
        const int n = m0 + row;
        const int2* sl = slots + (size_t)n * CAP;
        int deg = cnt[n];
        deg = deg > CAP ? CAP : deg;

        float4 acc = make_float4(0.0f, 0.0f, 0.0f, 0.0f);
        int sD0, sD1, sD2, sD3, iD0, iD1, iD2, iD3;
        float fD0, fD1, fD2, fD3;

        if (deg > 0) {
            const int nbF = deg >> 2;            // full 4-edge batches
            const int rem = deg & 3;
            const int totB = nbF + (rem ? 1 : 0);
            int dlast = deg - 1;
            int2 dscN = sl[min(l & 3, dlast)];

            int b = 0;
            for (; b < nbF; ++b) {
                GDESC4(dscN)
                if (b + 1 < totB) {
                    int idx = (b + 1) * 4 + (l & 3);
                    dscN = sl[idx < deg ? idx : dlast];
                }
                GLF(0) GLF(1) GLF(2) GLF(3)
            }
            if (rem) {                           // one clamped partial batch
                GDESC4(dscN)
                GLF(0)
                if (rem > 1) GLF(1)
                if (rem > 2) GLF(2)
            }
        }

        ushort4 st;
        st.x = f2bf(acc.x); st.y = f2bf(acc.y); st.z = f2bf(acc.z); st.w = f2bf(acc.w);
        *(ushort4*)&s_a[row * RS + c4] = st;
    }
    __syncthreads();

    // ---- phase 2: node MLP on the 16 staged rows (8 waves, 32 cols each) ----
    const int lr = l & 15, lg = l >> 4, nb = w * 32;
    f32x4 acc2[2];
    #pragma unroll
    for (int nt = 0; nt < 2; ++nt) acc2[nt] = (f32x4)0.0f;

    #pragma unroll 2
    for (int kt = 0; kt < 8; ++kt) {
        bf16x8 a = *(const bf16x8*)&s_a[lr * RS + kt * 32 + lg * 8];
        #pragma unroll
        for (int nt = 0; nt < 2; ++nt) {
            bf16x8 b = *(const bf16x8*)&w4p[(size_t)(((kt * 4 + lg) * 256) + nb + nt * 16 + lr) * 8];
            acc2[nt] = __builtin_amdgcn_mfma_f32_16x16x32_bf16(a, b, acc2[nt], 0, 0, 0);
        }
    }
    __syncthreads();

    #pragma unroll
    for (int nt = 0; nt < 2; ++nt) {
        int col = nb + nt * 16 + lr;
        float bias = b4[col];
        #pragma unroll
        for (int rr = 0; rr < 4; ++rr)
            s_a[(lg * 4 + rr) * RS + col] = f2bf(ssp_f(acc2[nt][rr] + bias));
    }
    __syncthreads();

    #pragma unroll
    for (int nt = 0; nt < 2; ++nt) acc2[nt] = (f32x4)0.0f;

    #pragma unroll 2
    for (int kt = 0; kt < 8; ++kt) {
        bf16x8 a = *(const bf16x8*)&s_a[lr * RS + kt * 32 + lg * 8];
        #pragma unroll
        for (int nt = 0; nt < 2; ++nt) {
            bf16x8 b = *(const bf16x8*)&w5p[(size_t)(((kt * 4 + lg) * 256) + nb + nt * 16 + lr) * 8];
            acc2[nt] = __builtin_amdgcn_mfma_f32_16x16x32_bf16(a, b, acc2[nt], 0, 0, 0);
        }
    }

    #pragma unroll
    for (int nt = 0; nt < 2; ++nt) {
        int col = nb + nt * 16 + lr;
        float bias = b5[col];
        #pragma unroll
        for (int rr = 0; rr < 4; ++rr) {
            int row = m0 + lg * 4 + rr;
            out[(size_t)row * CDIM + col] =
                acc2[nt][rr] + bias + x[(size_t)row * CDIM + col];
        }
    }
}

extern "C" void kernel_launch(void* const* d_in, const int* in_sizes, int n_in,
                              void* d_out, int out_size, void* d_ws, size_t ws_size,
                              hipStream_t stream) {
    const float* pos = (const float*)d_in[0];
    const float* x   = (const float*)d_in[1];
    const int*   snd = (const int*)d_in[2];
    const int*   rcv = (const int*)d_in[3];
    const float* w1  = (const float*)d_in[4];
    const float* b1  = (const float*)d_in[5];
    const float* w2  = (const float*)d_in[6];
    const float* b2  = (const float*)d_in[7];
    const float* w3  = (const float*)d_in[8];
    const float* w4  = (const float*)d_in[9];
    const float* b4  = (const float*)d_in[10];
    const float* w5  = (const float*)d_in[11];
    const float* b5  = (const float*)d_in[12];

    float* out  = (float*)d_out;

    // ws: xw3h bf16 | Wtbi bf16 2112x512 (interleaved) | w3p/w4p/w5p | w1p | w2p | cnt | slots
    unsigned char* ws = (unsigned char*)d_ws;
    unsigned short* xw3h = (unsigned short*)ws;
    size_t off = (size_t)NNODES * CDIM * 2;
    unsigned short* Wtbi = (unsigned short*)(ws + off); off += (size_t)TROWS * 512 * 2;
    unsigned short* w3p = (unsigned short*)(ws + off); off += 65536 * 2;
    unsigned short* w4p = (unsigned short*)(ws + off); off += 65536 * 2;
    unsigned short* w5p = (unsigned short*)(ws + off); off += 65536 * 2;
    unsigned short* w1p = (unsigned short*)(ws + off); off += 57344 * 2;
    unsigned short* w2p = (unsigned short*)(ws + off); off += 65536 * 2;
    int* cnt = (int*)(ws + off);                       off += (size_t)NNODES * 4;
    int2* slots = (int2*)(ws + off);

    packzero_kernel<<<PACKB + ZEROB, NTHR, 0, stream>>>(w3, w4, w5, w1, w2,
                                                        w3p, w4p, w5p, w1p, w2p,
                                                        (int4*)cnt);
    mega_kernel<<<TBLK2 + XW3B + FILLB, NTHR, 0, stream>>>(w1p, b1, w2p, b2, Wtbi,
                                                           x, w3p, xw3h,
                                                           pos, snd, rcv, cnt, slots);
    gathernode_kernel<<<GNB, GTHR, 0, stream>>>(cnt, slots, Wtbi, xw3h,
                                                w4p, b4, w5p, b5, x, out);
}

// Round 11
// 90.933 us; speedup vs baseline: 1.1730x; 1.1730x over previous
//
#include <hip/hip_runtime.h>
#include <math.h>

#define NNODES 20000
#define NEDGES 320000
#define CDIM   256
#define NC     200
#define NB     2048                 // lerp intervals; Wt rows alloc'd 2112 (66*32)
#define TROWS  2112
#define DRANGE 24.0f
#define DELTA  (DRANGE / (float)NB)
#define INVDEL ((float)NB / DRANGE)
#define NTHR   256
#define RS     264                  // LDS row stride in ushorts (528B)
#define CAP    48                   // bucket capacity per node (Poisson(16); P(deg>=48)~1e-11)
#define GNR    16                   // rows per fused gather+node tile

#define PACKB  1248
#define ZEROB  20
#define TBLK2  (TROWS / 32)                   // 66
#define XW3B2  (NNODES / 16)                  // 1250 (16-row xw3 tiles)
#define FILLB4 ((NEDGES / 4 + NTHR - 1) / NTHR)   // 313 (4 edges/thread)
#define GNB    (NNODES / GNR)                 // 1250

typedef __attribute__((ext_vector_type(8))) short bf16x8;
typedef __attribute__((ext_vector_type(4))) float f32x4;
typedef __attribute__((ext_vector_type(8))) unsigned short u16x8;

__device__ __forceinline__ unsigned short f2bf(float f) {
    unsigned int u = __float_as_uint(f);
    unsigned int r = (u + 0x7FFFu + ((u >> 16) & 1u)) >> 16;   // RNE
    return (unsigned short)r;
}
__device__ __forceinline__ float bf2f(unsigned short h) {
    return __uint_as_float(((unsigned int)h) << 16);
}
__device__ __forceinline__ float ssp_f(float x) {
    const float LOG2V = 0.6931471805599453f;
    if (x < 14.0f) return __logf(1.0f + __expf(x)) - LOG2V;
    return x - LOG2V;
}

// ---------- pack weights + zero cnt (one small kernel) ----------
__global__ __launch_bounds__(NTHR)
void packzero_kernel(const float* __restrict__ w3, const float* __restrict__ w4,
                     const float* __restrict__ w5, const float* __restrict__ w1,
                     const float* __restrict__ w2,
                     unsigned short* __restrict__ w3p, unsigned short* __restrict__ w4p,
                     unsigned short* __restrict__ w5p, unsigned short* __restrict__ w1p,
                     unsigned short* __restrict__ w2p,
                     int4* __restrict__ cnt4)
{
    if (blockIdx.x < PACKB) {
        int idx = blockIdx.x * NTHR + threadIdx.x;             // 0 .. 319487
        if (idx < 196608) {
            int m = idx >> 16;
            int r = idx & 65535;
            int j = r & 7, c = (r >> 3) & 255, lg = (r >> 11) & 3, kt = r >> 13;
            int k = kt * 32 + lg * 8 + j;
            const float* w = (m == 0) ? w3 : (m == 1) ? w4 : w5;
            unsigned short* wp = (m == 0) ? w3p : (m == 1) ? w4p : w5p;
            wp[r] = f2bf(w[k * CDIM + c]);
        } else if (idx < 253952) {
            int r = idx - 196608;                        // w1p: 224*256 = 57344
            int j = r & 7, c = (r >> 3) & 255, lg = (r >> 11) & 3, kt = r >> 13;
            int k = kt * 32 + lg * 8 + j;
            w1p[r] = (k < NC) ? f2bf(w1[k * CDIM + c]) : (unsigned short)0;
        } else {
            int r = idx - 253952;                        // w2p: 65536
            int j = r & 7, c = (r >> 3) & 255, lg = (r >> 11) & 3, kt = r >> 13;
            int k = kt * 32 + lg * 8 + j;
            w2p[r] = f2bf(w2[k * CDIM + c]);
        }
    } else {
        int i = (blockIdx.x - PACKB) * NTHR + threadIdx.x;
        if (i < NNODES / 4) cnt4[i] = make_int4(0, 0, 0, 0);
    }
}

// ---------- mega kernel: table (32-bin, 66 blk) + xw3 (16-row, 1250 blk) +
//            fill (4 edges/thread, 313 blk), co-resident ----------
// Table output INTERLEAVED: Wtbi[i][c][0..1] = {w[i], w[i+1]}.
__global__ __launch_bounds__(NTHR, 4)
void mega_kernel(const unsigned short* __restrict__ w1p, const float* __restrict__ b1,
                 const unsigned short* __restrict__ w2p, const float* __restrict__ b2,
                 unsigned short* __restrict__ Wtbi,
                 const float* __restrict__ x,
                 const unsigned short* __restrict__ w3p,
                 unsigned short* __restrict__ xw3h,
                 const float* __restrict__ pos,
                 const int* __restrict__ snd,
                 const int* __restrict__ rcv,
                 int* __restrict__ cnt,
                 int2* __restrict__ slots)
{
    __shared__ unsigned short s_a[32 * RS];      // 16896 B (table uses 32 rows)
    const int t = threadIdx.x;

    if (blockIdx.x < TBLK2) {
        // ----- filter table, 32 bins per block -----
        const int m0 = blockIdx.x * 32;
        const float cstep = 20.0f / 199.0f;

        {
            int row = t >> 3;
            int k0 = (t & 7) * 28;
            float d = (float)(m0 + row) * DELTA;
            #pragma unroll
            for (int j = 0; j < 28; ++j) {
                int k = k0 + j;
                float dd = d - (float)k * cstep;
                float v = (k < NC) ? __expf(-10.0f * dd * dd) : 0.0f;
                s_a[row * RS + k] = f2bf(v);
            }
        }
        __syncthreads();

        const int l = t & 63, w = t >> 6, lr = l & 15, lg = l >> 4, nb = w * 64;
        f32x4 acc[2][4];
        #pragma unroll
        for (int mt = 0; mt < 2; ++mt)
            #pragma unroll
            for (int nt = 0; nt < 4; ++nt) acc[mt][nt] = (f32x4)0.0f;

        // GEMM1: K = 224
        #pragma unroll 2
        for (int kt = 0; kt < 7; ++kt) {
            bf16x8 a[2];
            #pragma unroll
            for (int mt = 0; mt < 2; ++mt)
                a[mt] = *(const bf16x8*)&s_a[(mt * 16 + lr) * RS + kt * 32 + lg * 8];
            #pragma unroll
            for (int nt = 0; nt < 4; ++nt) {
                bf16x8 b = *(const bf16x8*)&w1p[(size_t)(((kt * 4 + lg) * 256) + nb + nt * 16 + lr) * 8];
                #pragma unroll
                for (int mt = 0; mt < 2; ++mt)
                    acc[mt][nt] = __builtin_amdgcn_mfma_f32_16x16x32_bf16(a[mt], b, acc[mt][nt], 0, 0, 0);
            }
        }
        __syncthreads();

        #pragma unroll
        for (int nt = 0; nt < 4; ++nt) {
            int col = nb + nt * 16 + lr;
            float bias = b1[col];
            #pragma unroll
            for (int mt = 0; mt < 2; ++mt)
                #pragma unroll
                for (int rr = 0; rr < 4; ++rr)
                    s_a[(mt * 16 + lg * 4 + rr) * RS + col] = f2bf(ssp_f(acc[mt][nt][rr] + bias));
        }
        __syncthreads();

        #pragma unroll
        for (int mt = 0; mt < 2; ++mt)
            #pragma unroll
            for (int nt = 0; nt < 4; ++nt) acc[mt][nt] = (f32x4)0.0f;

        // GEMM2: K = 256
        #pragma unroll 2
        for (int kt = 0; kt < 8; ++kt) {
            bf16x8 a[2];
            #pragma unroll
            for (int mt = 0; mt < 2; ++mt)
                a[mt] = *(const bf16x8*)&s_a[(mt * 16 + lr) * RS + kt * 32 + lg * 8];
            #pragma unroll
            for (int nt = 0; nt < 4; ++nt) {
                bf16x8 b = *(const bf16x8*)&w2p[(size_t)(((kt * 4 + lg) * 256) + nb + nt * 16 + lr) * 8];
                #pragma unroll
                for (int mt = 0; mt < 2; ++mt)
                    acc[mt][nt] = __builtin_amdgcn_mfma_f32_16x16x32_bf16(a[mt], b, acc[mt][nt], 0, 0, 0);
            }
        }

        #pragma unroll
        for (int nt = 0; nt < 4; ++nt) {
            int col = nb + nt * 16 + lr;
            float bias = b2[col];
            #pragma unroll
            for (int mt = 0; mt < 2; ++mt)
                #pragma unroll
                for (int rr = 0; rr < 4; ++rr) {
                    int row = m0 + mt * 16 + lg * 4 + rr;
                    unsigned short v = f2bf(ssp_f(acc[mt][nt][rr] + bias));
                    Wtbi[(size_t)row * 512 + col * 2] = v;                   // slot 0 of row
                    if (row > 0)
                        Wtbi[(size_t)(row - 1) * 512 + col * 2 + 1] = v;     // slot 1 of row-1
                }
        }
    } else if (blockIdx.x < TBLK2 + XW3B2) {
        // ----- xw3 = x @ w3, 16 rows per block (1250 blocks) -----
        const int m0 = (blockIdx.x - TBLK2) * 16;

        {
            int row = t >> 4, c0 = (t & 15) * 16;
            const float* src = &x[(size_t)(m0 + row) * CDIM + c0];
            unsigned short* dst = &s_a[row * RS + c0];
            #pragma unroll
            for (int oc = 0; oc < 2; ++oc) {
                float4 a = *(const float4*)&src[oc * 8];
                float4 b = *(const float4*)&src[oc * 8 + 4];
                u16x8 v;
                v[0] = f2bf(a.x); v[1] = f2bf(a.y); v[2] = f2bf(a.z); v[3] = f2bf(a.w);
                v[4] = f2bf(b.x); v[5] = f2bf(b.y); v[6] = f2bf(b.z); v[7] = f2bf(b.w);
                *(u16x8*)&dst[oc * 8] = v;
            }
        }
        __syncthreads();

        const int l = t & 63, w = t >> 6, lr = l & 15, lg = l >> 4, nb = w * 64;
        f32x4 acc2[4];
        #pragma unroll
        for (int nt = 0; nt < 4; ++nt) acc2[nt] = (f32x4)0.0f;

        #pragma unroll 2
        for (int kt = 0; kt < 8; ++kt) {
            bf16x8 a = *(const bf16x8*)&s_a[lr * RS + kt * 32 + lg * 8];
            #pragma unroll
            for (int nt = 0; nt < 4; ++nt) {
                bf16x8 b = *(const bf16x8*)&w3p[(size_t)(((kt * 4 + lg) * 256) + nb + nt * 16 + lr) * 8];
                acc2[nt] = __builtin_amdgcn_mfma_f32_16x16x32_bf16(a, b, acc2[nt], 0, 0, 0);
            }
        }

        #pragma unroll
        for (int nt = 0; nt < 4; ++nt) {
            int col = nb + nt * 16 + lr;
            #pragma unroll
            for (int rr = 0; rr < 4; ++rr) {
                int row = m0 + lg * 4 + rr;
                xw3h[(size_t)row * CDIM + col] = f2bf(acc2[nt][rr]);
            }
        }
    } else {
        // ----- fill: edge bucketing, 4 edges per thread (313 blocks) -----
        int g = (blockIdx.x - TBLK2 - XW3B2) * NTHR + threadIdx.x;   // int4 index
        if (g >= NEDGES / 4) return;
        int4 s4 = *(const int4*)&snd[g * 4];
        int4 r4 = *(const int4*)&rcv[g * 4];
        int ss[4] = { s4.x, s4.y, s4.z, s4.w };
        int rr_[4] = { r4.x, r4.y, r4.z, r4.w };
        float psx[4], psy[4], psz[4], prx[4], pry[4], prz[4];
        #pragma unroll
        for (int q = 0; q < 4; ++q) {
            psx[q] = pos[ss[q] * 3 + 0]; psy[q] = pos[ss[q] * 3 + 1]; psz[q] = pos[ss[q] * 3 + 2];
            prx[q] = pos[rr_[q] * 3 + 0]; pry[q] = pos[rr_[q] * 3 + 1]; prz[q] = pos[rr_[q] * 3 + 2];
        }
        #pragma unroll
        for (int q = 0; q < 4; ++q) {
            float dx = prx[q] - psx[q];
            float dy = pry[q] - psy[q];
            float dz = prz[q] - psz[q];
            float d = sqrtf(dx * dx + dy * dy + dz * dz);
            float u = fminf(d * INVDEL, (float)NB - 0.001f);
            int rank = atomicAdd(&cnt[rr_[q]], 1);
            if (rank < CAP) {
                int2 v; v.x = ss[q]; v.y = __float_as_int(u);
                slots[(size_t)rr_[q] * CAP + rank] = v;
            }
        }
    }
}

// ---------- fused gather + node MLP: 16 nodes per block (round-9 proven form) ------
// Phase 1 (gather): wave w accumulates conv for rows w*4..w*4+3 (4 ch/lane, one 16B
// interleaved-table load + one 8B feature load per edge), writes bf16 into s_a.
// Phase 2 (MLP):   out = x + ssp(conv@w4+b4) @ w5 + b5 straight from s_a.
// Blocks at phase 1 (VMEM-latency) overlap blocks at phase 2 (MFMA) on each CU.
// NOTE (R1/R8/R10 lesson): do NOT cut the VGPR budget below (256,4) — gather needs
// ~40 VGPR for its in-flight load batch; occupancy gained below that is a net loss.

#define GDESC4(src) { \
    sD0 = __shfl((src).x, 0); sD1 = __shfl((src).x, 1); \
    sD2 = __shfl((src).x, 2); sD3 = __shfl((src).x, 3); \
    float u0_ = __int_as_float(__shfl((src).y, 0)); iD0 = (int)u0_; fD0 = u0_ - (float)iD0; \
    float u1_ = __int_as_float(__shfl((src).y, 1)); iD1 = (int)u1_; fD1 = u1_ - (float)iD1; \
    float u2_ = __int_as_float(__shfl((src).y, 2)); iD2 = (int)u2_; fD2 = u2_ - (float)iD2; \
    float u3_ = __int_as_float(__shfl((src).y, 3)); iD3 = (int)u3_; fD3 = u3_ - (float)iD3; }

#define GLF(e) { \
    u16x8 wab = *(const u16x8*)&Wtbi[(size_t)iD##e * 512 + c8]; \
    ushort4 fx = *(const ushort4*)&xw3h[(size_t)sD##e * CDIM + c4]; \
    float a0, a1; \
    a0 = bf2f(wab[0]); a1 = bf2f(wab[1]); acc.x = fmaf(fmaf(fD##e, a1 - a0, a0), bf2f(fx.x), acc.x); \
    a0 = bf2f(wab[2]); a1 = bf2f(wab[3]); acc.y = fmaf(fmaf(fD##e, a1 - a0, a0), bf2f(fx.y), acc.y); \
    a0 = bf2f(wab[4]); a1 = bf2f(wab[5]); acc.z = fmaf(fmaf(fD##e, a1 - a0, a0), bf2f(fx.z), acc.z); \
    a0 = bf2f(wab[6]); a1 = bf2f(wab[7]); acc.w = fmaf(fmaf(fD##e, a1 - a0, a0), bf2f(fx.w), acc.w); }

__global__ __launch_bounds__(NTHR, 4)
void gathernode_kernel(const int* __restrict__ cnt,
                       const int2* __restrict__ slots,
                       const unsigned short* __restrict__ Wtbi,
                       const unsigned short* __restrict__ xw3h,
                       const unsigned short* __restrict__ w4p, const float* __restrict__ b4,
                       const unsigned short* __restrict__ w5p, const float* __restrict__ b5,
                       const float* __restrict__ x,
                       float* __restrict__ out)
{
    __shared__ unsigned short s_a[GNR * RS];     // 8448 B
    const int t = threadIdx.x;
    const int w = t >> 6, l = t & 63;
    const int c4 = l * 4;          // channel offset (ushorts) in xw3h / s_a rows
    const int c8 = l * 8;          // offset (ushorts) in interleaved Wtbi row
    const int m0 = blockIdx.x * GNR;             // NNODES % 16 == 0 -> no guards

    // ---- phase 1: gather 4 nodes per wave ----
    for (int rr = 0; rr < 4; ++rr) {
        const int row = w * 4 + rr;
        const int n = m0 + row;
        const int2* sl = slots + (size_t)n * CAP;
        int deg = cnt[n];
        deg = deg > CAP ? CAP : deg;

        float4 acc = make_float4(0.0f, 0.0f, 0.0f, 0.0f);
        int sD0, sD1, sD2, sD3, iD0, iD1, iD2, iD3;
        float fD0, fD1, fD2, fD3;

        int j = 0;
        int2 dscN = make_int2(0, 0);
        if (deg >= 4) dscN = sl[l & 3];
        while (j + 4 <= deg) {
            GDESC4(dscN)
            if (j + 8 <= deg) dscN = sl[j + 4 + (l & 3)];   // next batch descriptors
            GLF(0) GLF(1) GLF(2) GLF(3)
            j += 4;
        }
        for (; j < deg; ++j) {                               // serial tail (<= 3)
            int2 sv = sl[j];
            float u = __int_as_float(sv.y);
            int i = (int)u;
            float fr = u - (float)i;
            u16x8 wab = *(const u16x8*)&Wtbi[(size_t)i * 512 + c8];
            ushort4 fx = *(const ushort4*)&xw3h[(size_t)sv.x * CDIM + c4];
            float a0, a1;
            a0 = bf2f(wab[0]); a1 = bf2f(wab[1]); acc.x = fmaf(fmaf(fr, a1 - a0, a0), bf2f(fx.x), acc.x);
            a0 = bf2f(wab[2]); a1 = bf2f(wab[3]); acc.y = fmaf(fmaf(fr, a1 - a0, a0), bf2f(fx.y), acc.y);
            a0 = bf2f(wab[4]); a1 = bf2f(wab[5]); acc.z = fmaf(fmaf(fr, a1 - a0, a0), bf2f(fx.z), acc.z);
            a0 = bf2f(wab[6]); a1 = bf2f(wab[7]); acc.w = fmaf(fmaf(fr, a1 - a0, a0), bf2f(fx.w), acc.w);
        }

        ushort4 st;
        st.x = f2bf(acc.x); st.y = f2bf(acc.y); st.z = f2bf(acc.z); st.w = f2bf(acc.w);
        *(ushort4*)&s_a[row * RS + c4] = st;
    }
    __syncthreads();

    // ---- phase 2: node MLP on the 16 staged rows ----
    const int lr = l & 15, lg = l >> 4, nb = w * 64;
    f32x4 acc2[4];
    #pragma unroll
    for (int nt = 0; nt < 4; ++nt) acc2[nt] = (f32x4)0.0f;

    #pragma unroll 2
    for (int kt = 0; kt < 8; ++kt) {
        bf16x8 a = *(const bf16x8*)&s_a[lr * RS + kt * 32 + lg * 8];
        #pragma unroll
        for (int nt = 0; nt < 4; ++nt) {
            bf16x8 b = *(const bf16x8*)&w4p[(size_t)(((kt * 4 + lg) * 256) + nb + nt * 16 + lr) * 8];
            acc2[nt] = __builtin_amdgcn_mfma_f32_16x16x32_bf16(a, b, acc2[nt], 0, 0, 0);
        }
    }
    __syncthreads();

    #pragma unroll
    for (int nt = 0; nt < 4; ++nt) {
        int col = nb + nt * 16 + lr;
        float bias = b4[col];
        #pragma unroll
        for (int rr = 0; rr < 4; ++rr)
            s_a[(lg * 4 + rr) * RS + col] = f2bf(ssp_f(acc2[nt][rr] + bias));
    }
    __syncthreads();

    #pragma unroll
    for (int nt = 0; nt < 4; ++nt) acc2[nt] = (f32x4)0.0f;

    #pragma unroll 2
    for (int kt = 0; kt < 8; ++kt) {
        bf16x8 a = *(const bf16x8*)&s_a[lr * RS + kt * 32 + lg * 8];
        #pragma unroll
        for (int nt = 0; nt < 4; ++nt) {
            bf16x8 b = *(const bf16x8*)&w5p[(size_t)(((kt * 4 + lg) * 256) + nb + nt * 16 + lr) * 8];
            acc2[nt] = __builtin_amdgcn_mfma_f32_16x16x32_bf16(a, b, acc2[nt], 0, 0, 0);
        }
    }

    #pragma unroll
    for (int nt = 0; nt < 4; ++nt) {
        int col = nb + nt * 16 + lr;
        float bias = b5[col];
        #pragma unroll
        for (int rr = 0; rr < 4; ++rr) {
            int row = m0 + lg * 4 + rr;
            out[(size_t)row * CDIM + col] =
                acc2[nt][rr] + bias + x[(size_t)row * CDIM + col];
        }
    }
}

extern "C" void kernel_launch(void* const* d_in, const int* in_sizes, int n_in,
                              void* d_out, int out_size, void* d_ws, size_t ws_size,
                              hipStream_t stream) {
    const float* pos = (const float*)d_in[0];
    const float* x   = (const float*)d_in[1];
    const int*   snd = (const int*)d_in[2];
    const int*   rcv = (const int*)d_in[3];
    const float* w1  = (const float*)d_in[4];
    const float* b1  = (const float*)d_in[5];
    const float* w2  = (const float*)d_in[6];
    const float* b2  = (const float*)d_in[7];
    const float* w3  = (const float*)d_in[8];
    const float* w4  = (const float*)d_in[9];
    const float* b4  = (const float*)d_in[10];
    const float* w5  = (const float*)d_in[11];
    const float* b5  = (const float*)d_in[12];

    float* out  = (float*)d_out;

    // ws: xw3h bf16 | Wtbi bf16 2112x512 (interleaved) | w3p/w4p/w5p | w1p | w2p | cnt | slots
    unsigned char* ws = (unsigned char*)d_ws;
    unsigned short* xw3h = (unsigned short*)ws;
    size_t off = (size_t)NNODES * CDIM * 2;
    unsigned short* Wtbi = (unsigned short*)(ws + off); off += (size_t)TROWS * 512 * 2;
    unsigned short* w3p = (unsigned short*)(ws + off); off += 65536 * 2;
    unsigned short* w4p = (unsigned short*)(ws + off); off += 65536 * 2;
    unsigned short* w5p = (unsigned short*)(ws + off); off += 65536 * 2;
    unsigned short* w1p = (unsigned short*)(ws + off); off += 57344 * 2;
    unsigned short* w2p = (unsigned short*)(ws + off); off += 65536 * 2;
    int* cnt = (int*)(ws + off);                       off += (size_t)NNODES * 4;
    int2* slots = (int2*)(ws + off);

    packzero_kernel<<<PACKB + ZEROB, NTHR, 0, stream>>>(w3, w4, w5, w1, w2,
                                                        w3p, w4p, w5p, w1p, w2p,
                                                        (int4*)cnt);
    mega_kernel<<<TBLK2 + XW3B2 + FILLB4, NTHR, 0, stream>>>(w1p, b1, w2p, b2, Wtbi,
                                                             x, w3p, xw3h,
                                                             pos, snd, rcv, cnt, slots);
    gathernode_kernel<<<GNB, NTHR, 0, stream>>>(cnt, slots, Wtbi, xw3h,
                                                w4p, b4, w5p, b5, x, out);
}

// Round 12
// 84.435 us; speedup vs baseline: 1.2633x; 1.0769x over previous
//
#include <hip/hip_runtime.h>
#include <math.h>

#define NNODES 20000
#define NEDGES 320000
#define CDIM   256
#define NC     200
#define NB     4096                 // nearest-neighbor bins; rows alloc'd 4160 (130*32)
#define TROWS  4160
#define DRANGE 24.0f
#define DELTA  (DRANGE / (float)NB)
#define INVDEL ((float)NB / DRANGE)
#define NTHR   256
#define RS     264                  // LDS row stride in ushorts (528B)
#define CAP    48                   // bucket capacity per node (Poisson(16); P(deg>=48)~1e-11)
#define GNR    16                   // rows per fused gather+node tile

#define PACKB  1248
#define ZEROB  20
#define TBLK2  (TROWS / 32)                   // 130
#define XW3B2  (NNODES / 16)                  // 1250 (16-row xw3 tiles)
#define FILLB4 ((NEDGES / 4 + NTHR - 1) / NTHR)   // 313 (4 edges/thread)
#define GNB    (NNODES / GNR)                 // 1250

typedef __attribute__((ext_vector_type(8))) short bf16x8;
typedef __attribute__((ext_vector_type(4))) float f32x4;
typedef __attribute__((ext_vector_type(8))) unsigned short u16x8;

__device__ __forceinline__ unsigned short f2bf(float f) {
    unsigned int u = __float_as_uint(f);
    unsigned int r = (u + 0x7FFFu + ((u >> 16) & 1u)) >> 16;   // RNE
    return (unsigned short)r;
}
__device__ __forceinline__ float bf2f(unsigned short h) {
    return __uint_as_float(((unsigned int)h) << 16);
}
__device__ __forceinline__ float ssp_f(float x) {
    const float LOG2V = 0.6931471805599453f;
    if (x < 14.0f) return __logf(1.0f + __expf(x)) - LOG2V;
    return x - LOG2V;
}

// ---------- pack weights + zero cnt (one small kernel) ----------
__global__ __launch_bounds__(NTHR)
void packzero_kernel(const float* __restrict__ w3, const float* __restrict__ w4,
                     const float* __restrict__ w5, const float* __restrict__ w1,
                     const float* __restrict__ w2,
                     unsigned short* __restrict__ w3p, unsigned short* __restrict__ w4p,
                     unsigned short* __restrict__ w5p, unsigned short* __restrict__ w1p,
                     unsigned short* __restrict__ w2p,
                     int4* __restrict__ cnt4)
{
    if (blockIdx.x < PACKB) {
        int idx = blockIdx.x * NTHR + threadIdx.x;             // 0 .. 319487
        if (idx < 196608) {
            int m = idx >> 16;
            int r = idx & 65535;
            int j = r & 7, c = (r >> 3) & 255, lg = (r >> 11) & 3, kt = r >> 13;
            int k = kt * 32 + lg * 8 + j;
            const float* w = (m == 0) ? w3 : (m == 1) ? w4 : w5;
            unsigned short* wp = (m == 0) ? w3p : (m == 1) ? w4p : w5p;
            wp[r] = f2bf(w[k * CDIM + c]);
        } else if (idx < 253952) {
            int r = idx - 196608;                        // w1p: 224*256 = 57344
            int j = r & 7, c = (r >> 3) & 255, lg = (r >> 11) & 3, kt = r >> 13;
            int k = kt * 32 + lg * 8 + j;
            w1p[r] = (k < NC) ? f2bf(w1[k * CDIM + c]) : (unsigned short)0;
        } else {
            int r = idx - 253952;                        // w2p: 65536
            int j = r & 7, c = (r >> 3) & 255, lg = (r >> 11) & 3, kt = r >> 13;
            int k = kt * 32 + lg * 8 + j;
            w2p[r] = f2bf(w2[k * CDIM + c]);
        }
    } else {
        int i = (blockIdx.x - PACKB) * NTHR + threadIdx.x;
        if (i < NNODES / 4) cnt4[i] = make_int4(0, 0, 0, 0);
    }
}

// ---------- mega kernel: table (32-bin, 130 blk) + xw3 (16-row, 1250 blk) +
//            fill (4 edges/thread, 313 blk), co-resident ----------
// Table is NON-interleaved [TROWS][256]; gather does nearest-neighbor lookup
// (NB=4096 bins, delta=24/4096 -> nearest error ~Delta/2=0.003 in d, damped by
// the small-weight node MLP to ~1e-3 at the output; lerp no longer needed).
__global__ __launch_bounds__(NTHR, 4)
void mega_kernel(const unsigned short* __restrict__ w1p, const float* __restrict__ b1,
                 const unsigned short* __restrict__ w2p, const float* __restrict__ b2,
                 unsigned short* __restrict__ Wtb,
                 const float* __restrict__ x,
                 const unsigned short* __restrict__ w3p,
                 unsigned short* __restrict__ xw3h,
                 const float* __restrict__ pos,
                 const int* __restrict__ snd,
                 const int* __restrict__ rcv,
                 int* __restrict__ cnt,
                 int2* __restrict__ slots)
{
    __shared__ unsigned short s_a[32 * RS];      // 16896 B (table uses 32 rows)
    const int t = threadIdx.x;

    if (blockIdx.x < TBLK2) {
        // ----- filter table, 32 bins per block -----
        const int m0 = blockIdx.x * 32;
        const float cstep = 20.0f / 199.0f;

        {
            int row = t >> 3;
            int k0 = (t & 7) * 28;
            float d = (float)(m0 + row) * DELTA;
            #pragma unroll
            for (int j = 0; j < 28; ++j) {
                int k = k0 + j;
                float dd = d - (float)k * cstep;
                float v = (k < NC) ? __expf(-10.0f * dd * dd) : 0.0f;
                s_a[row * RS + k] = f2bf(v);
            }
        }
        __syncthreads();

        const int l = t & 63, w = t >> 6, lr = l & 15, lg = l >> 4, nb = w * 64;
        f32x4 acc[2][4];
        #pragma unroll
        for (int mt = 0; mt < 2; ++mt)
            #pragma unroll
            for (int nt = 0; nt < 4; ++nt) acc[mt][nt] = (f32x4)0.0f;

        // GEMM1: K = 224
        #pragma unroll 2
        for (int kt = 0; kt < 7; ++kt) {
            bf16x8 a[2];
            #pragma unroll
            for (int mt = 0; mt < 2; ++mt)
                a[mt] = *(const bf16x8*)&s_a[(mt * 16 + lr) * RS + kt * 32 + lg * 8];
            #pragma unroll
            for (int nt = 0; nt < 4; ++nt) {
                bf16x8 b = *(const bf16x8*)&w1p[(size_t)(((kt * 4 + lg) * 256) + nb + nt * 16 + lr) * 8];
                #pragma unroll
                for (int mt = 0; mt < 2; ++mt)
                    acc[mt][nt] = __builtin_amdgcn_mfma_f32_16x16x32_bf16(a[mt], b, acc[mt][nt], 0, 0, 0);
            }
        }
        __syncthreads();

        #pragma unroll
        for (int nt = 0; nt < 4; ++nt) {
            int col = nb + nt * 16 + lr;
            float bias = b1[col];
            #pragma unroll
            for (int mt = 0; mt < 2; ++mt)
                #pragma unroll
                for (int rr = 0; rr < 4; ++rr)
                    s_a[(mt * 16 + lg * 4 + rr) * RS + col] = f2bf(ssp_f(acc[mt][nt][rr] + bias));
        }
        __syncthreads();

        #pragma unroll
        for (int mt = 0; mt < 2; ++mt)
            #pragma unroll
            for (int nt = 0; nt < 4; ++nt) acc[mt][nt] = (f32x4)0.0f;

        // GEMM2: K = 256
        #pragma unroll 2
        for (int kt = 0; kt < 8; ++kt) {
            bf16x8 a[2];
            #pragma unroll
            for (int mt = 0; mt < 2; ++mt)
                a[mt] = *(const bf16x8*)&s_a[(mt * 16 + lr) * RS + kt * 32 + lg * 8];
            #pragma unroll
            for (int nt = 0; nt < 4; ++nt) {
                bf16x8 b = *(const bf16x8*)&w2p[(size_t)(((kt * 4 + lg) * 256) + nb + nt * 16 + lr) * 8];
                #pragma unroll
                for (int mt = 0; mt < 2; ++mt)
                    acc[mt][nt] = __builtin_amdgcn_mfma_f32_16x16x32_bf16(a[mt], b, acc[mt][nt], 0, 0, 0);
            }
        }

        #pragma unroll
        for (int nt = 0; nt < 4; ++nt) {
            int col = nb + nt * 16 + lr;
            float bias = b2[col];
            #pragma unroll
            for (int mt = 0; mt < 2; ++mt)
                #pragma unroll
                for (int rr = 0; rr < 4; ++rr) {
                    int row = m0 + mt * 16 + lg * 4 + rr;
                    Wtb[(size_t)row * CDIM + col] = f2bf(ssp_f(acc[mt][nt][rr] + bias));
                }
        }
    } else if (blockIdx.x < TBLK2 + XW3B2) {
        // ----- xw3 = x @ w3, 16 rows per block (1250 blocks) -----
        const int m0 = (blockIdx.x - TBLK2) * 16;

        {
            int row = t >> 4, c0 = (t & 15) * 16;
            const float* src = &x[(size_t)(m0 + row) * CDIM + c0];
            unsigned short* dst = &s_a[row * RS + c0];
            #pragma unroll
            for (int oc = 0; oc < 2; ++oc) {
                float4 a = *(const float4*)&src[oc * 8];
                float4 b = *(const float4*)&src[oc * 8 + 4];
                u16x8 v;
                v[0] = f2bf(a.x); v[1] = f2bf(a.y); v[2] = f2bf(a.z); v[3] = f2bf(a.w);
                v[4] = f2bf(b.x); v[5] = f2bf(b.y); v[6] = f2bf(b.z); v[7] = f2bf(b.w);
                *(u16x8*)&dst[oc * 8] = v;
            }
        }
        __syncthreads();

        const int l = t & 63, w = t >> 6, lr = l & 15, lg = l >> 4, nb = w * 64;
        f32x4 acc2[4];
        #pragma unroll
        for (int nt = 0; nt < 4; ++nt) acc2[nt] = (f32x4)0.0f;

        #pragma unroll 2
        for (int kt = 0; kt < 8; ++kt) {
            bf16x8 a = *(const bf16x8*)&s_a[lr * RS + kt * 32 + lg * 8];
            #pragma unroll
            for (int nt = 0; nt < 4; ++nt) {
                bf16x8 b = *(const bf16x8*)&w3p[(size_t)(((kt * 4 + lg) * 256) + nb + nt * 16 + lr) * 8];
                acc2[nt] = __builtin_amdgcn_mfma_f32_16x16x32_bf16(a, b, acc2[nt], 0, 0, 0);
            }
        }

        #pragma unroll
        for (int nt = 0; nt < 4; ++nt) {
            int col = nb + nt * 16 + lr;
            #pragma unroll
            for (int rr = 0; rr < 4; ++rr) {
                int row = m0 + lg * 4 + rr;
                xw3h[(size_t)row * CDIM + col] = f2bf(acc2[nt][rr]);
            }
        }
    } else {
        // ----- fill: edge bucketing, 4 edges per thread (313 blocks) -----
        // Slot stores {sender, nearest table index}.
        int g = (blockIdx.x - TBLK2 - XW3B2) * NTHR + threadIdx.x;   // int4 index
        if (g >= NEDGES / 4) return;
        int4 s4 = *(const int4*)&snd[g * 4];
        int4 r4 = *(const int4*)&rcv[g * 4];
        int ss[4] = { s4.x, s4.y, s4.z, s4.w };
        int rr_[4] = { r4.x, r4.y, r4.z, r4.w };
        float psx[4], psy[4], psz[4], prx[4], pry[4], prz[4];
        #pragma unroll
        for (int q = 0; q < 4; ++q) {
            psx[q] = pos[ss[q] * 3 + 0]; psy[q] = pos[ss[q] * 3 + 1]; psz[q] = pos[ss[q] * 3 + 2];
            prx[q] = pos[rr_[q] * 3 + 0]; pry[q] = pos[rr_[q] * 3 + 1]; prz[q] = pos[rr_[q] * 3 + 2];
        }
        #pragma unroll
        for (int q = 0; q < 4; ++q) {
            float dx = prx[q] - psx[q];
            float dy = pry[q] - psy[q];
            float dz = prz[q] - psz[q];
            float d = sqrtf(dx * dx + dy * dy + dz * dz);
            float u = fminf(d * INVDEL, (float)NB - 1.0f);
            int idx = (int)(u + 0.5f);
            if (idx > NB - 1) idx = NB - 1;
            int rank = atomicAdd(&cnt[rr_[q]], 1);
            if (rank < CAP) {
                int2 v; v.x = ss[q]; v.y = idx;
                slots[(size_t)rr_[q] * CAP + rank] = v;
            }
        }
    }
}

// ---------- fused gather + node MLP: 16 nodes per block ----------
// Phase 1 (gather): wave w accumulates conv for rows w*4..w*4+3; per edge ONE 8B
// nearest-table load + ONE 8B feature load per lane (16 cache lines/edge vs 24
// with the lerp table -> line-count equilibrium predicts ~33% faster gather).
// 8-edge batches (R3-proven structure); descriptors prefetched one batch ahead.
// Phase 2 (MLP): out = x + ssp(conv@w4+b4) @ w5 + b5 from the LDS-staged rows.
// NOTE (R1/R8/R10 lesson): keep (256,4) — cutting gather below ~40 VGPR loses.

#define GDESC8(src) { \
    sD0 = __shfl((src).x, 0); iD0 = __shfl((src).y, 0); \
    sD1 = __shfl((src).x, 1); iD1 = __shfl((src).y, 1); \
    sD2 = __shfl((src).x, 2); iD2 = __shfl((src).y, 2); \
    sD3 = __shfl((src).x, 3); iD3 = __shfl((src).y, 3); \
    sD4 = __shfl((src).x, 4); iD4 = __shfl((src).y, 4); \
    sD5 = __shfl((src).x, 5); iD5 = __shfl((src).y, 5); \
    sD6 = __shfl((src).x, 6); iD6 = __shfl((src).y, 6); \
    sD7 = __shfl((src).x, 7); iD7 = __shfl((src).y, 7); }

#define GDESC4(src) { \
    sD0 = __shfl((src).x, 0); iD0 = __shfl((src).y, 0); \
    sD1 = __shfl((src).x, 1); iD1 = __shfl((src).y, 1); \
    sD2 = __shfl((src).x, 2); iD2 = __shfl((src).y, 2); \
    sD3 = __shfl((src).x, 3); iD3 = __shfl((src).y, 3); }

#define GLOAD1(e) \
    ushort4 wa##e = *(const ushort4*)&Wtb[(size_t)iD##e * CDIM + c4]; \
    ushort4 fx##e = *(const ushort4*)&xw3h[(size_t)sD##e * CDIM + c4];

#define GFMA1(e) { \
    acc.x = fmaf(bf2f(wa##e.x), bf2f(fx##e.x), acc.x); \
    acc.y = fmaf(bf2f(wa##e.y), bf2f(fx##e.y), acc.y); \
    acc.z = fmaf(bf2f(wa##e.z), bf2f(fx##e.z), acc.z); \
    acc.w = fmaf(bf2f(wa##e.w), bf2f(fx##e.w), acc.w); }

__global__ __launch_bounds__(NTHR, 4)
void gathernode_kernel(const int* __restrict__ cnt,
                       const int2* __restrict__ slots,
                       const unsigned short* __restrict__ Wtb,
                       const unsigned short* __restrict__ xw3h,
                       const unsigned short* __restrict__ w4p, const float* __restrict__ b4,
                       const unsigned short* __restrict__ w5p, const float* __restrict__ b5,
                       const float* __restrict__ x,
                       float* __restrict__ out)
{
    __shared__ unsigned short s_a[GNR * RS];     // 8448 B
    const int t = threadIdx.x;
    const int w = t >> 6, l = t & 63;
    const int c4 = l * 4;          // channel offset (ushorts) in Wtb / xw3h / s_a rows
    const int m0 = blockIdx.x * GNR;             // NNODES % 16 == 0 -> no guards

    // ---- phase 1: gather 4 nodes per wave ----
    for (int rr = 0; rr < 4; ++rr) {
        const int row = w * 4 + rr;
        const int n = m0 + row;
        const int2* sl = slots + (size_t)n * CAP;
        int deg = cnt[n];
        deg = deg > CAP ? CAP : deg;

        float4 acc = make_float4(0.0f, 0.0f, 0.0f, 0.0f);
        int sD0, sD1, sD2, sD3, sD4, sD5, sD6, sD7;
        int iD0, iD1, iD2, iD3, iD4, iD5, iD6, iD7;

        int j = 0;
        int2 dscN = make_int2(0, 0);
        if (deg >= 8) dscN = sl[l & 7];

        while (j + 8 <= deg) {
            GDESC8(dscN)
            if (j + 16 <= deg) dscN = sl[j + 8 + (l & 7)];   // next batch descriptors
            GLOAD1(0) GLOAD1(1) GLOAD1(2) GLOAD1(3)
            GLOAD1(4) GLOAD1(5) GLOAD1(6) GLOAD1(7)
            GFMA1(0) GFMA1(1) GFMA1(2) GFMA1(3)
            GFMA1(4) GFMA1(5) GFMA1(6) GFMA1(7)
            j += 8;
        }

        if (j + 4 <= deg) {
            int2 d4 = sl[j + (l & 3)];
            GDESC4(d4)
            GLOAD1(0) GLOAD1(1) GLOAD1(2) GLOAD1(3)
            GFMA1(0) GFMA1(1) GFMA1(2) GFMA1(3)
            j += 4;
        }

        // serial tail (<= 3 edges): loads first, then FMAs
        {
            int rem = deg - j;
            if (rem > 0) {
                int2 sv0 = sl[j];
                sD0 = sv0.x; iD0 = sv0.y;
                GLOAD1(0)
                if (rem > 1) {
                    int2 sv1 = sl[j + 1];
                    sD1 = sv1.x; iD1 = sv1.y;
                    GLOAD1(1)
                    if (rem > 2) {
                        int2 sv2 = sl[j + 2];
                        sD2 = sv2.x; iD2 = sv2.y;
                        GLOAD1(2)
                        GFMA1(2)
                    }
                    GFMA1(1)
                }
                GFMA1(0)
            }
        }

        ushort4 st;
        st.x = f2bf(acc.x); st.y = f2bf(acc.y); st.z = f2bf(acc.z); st.w = f2bf(acc.w);
        *(ushort4*)&s_a[row * RS + c4] = st;
    }
    __syncthreads();

    // ---- phase 2: node MLP on the 16 staged rows ----
    const int lr = l & 15, lg = l >> 4, nb = w * 64;
    f32x4 acc2[4];
    #pragma unroll
    for (int nt = 0; nt < 4; ++nt) acc2[nt] = (f32x4)0.0f;

    #pragma unroll 2
    for (int kt = 0; kt < 8; ++kt) {
        bf16x8 a = *(const bf16x8*)&s_a[lr * RS + kt * 32 + lg * 8];
        #pragma unroll
        for (int nt = 0; nt < 4; ++nt) {
            bf16x8 b = *(const bf16x8*)&w4p[(size_t)(((kt * 4 + lg) * 256) + nb + nt * 16 + lr) * 8];
            acc2[nt] = __builtin_amdgcn_mfma_f32_16x16x32_bf16(a, b, acc2[nt], 0, 0, 0);
        }
    }
    __syncthreads();

    #pragma unroll
    for (int nt = 0; nt < 4; ++nt) {
        int col = nb + nt * 16 + lr;
        float bias = b4[col];
        #pragma unroll
        for (int rr = 0; rr < 4; ++rr)
            s_a[(lg * 4 + rr) * RS + col] = f2bf(ssp_f(acc2[nt][rr] + bias));
    }
    __syncthreads();

    #pragma unroll
    for (int nt = 0; nt < 4; ++nt) acc2[nt] = (f32x4)0.0f;

    #pragma unroll 2
    for (int kt = 0; kt < 8; ++kt) {
        bf16x8 a = *(const bf16x8*)&s_a[lr * RS + kt * 32 + lg * 8];
        #pragma unroll
        for (int nt = 0; nt < 4; ++nt) {
            bf16x8 b = *(const bf16x8*)&w5p[(size_t)(((kt * 4 + lg) * 256) + nb + nt * 16 + lr) * 8];
            acc2[nt] = __builtin_amdgcn_mfma_f32_16x16x32_bf16(a, b, acc2[nt], 0, 0, 0);
        }
    }

    #pragma unroll
    for (int nt = 0; nt < 4; ++nt) {
        int col = nb + nt * 16 + lr;
        float bias = b5[col];
        #pragma unroll
        for (int rr = 0; rr < 4; ++rr) {
            int row = m0 + lg * 4 + rr;
            out[(size_t)row * CDIM + col] =
                acc2[nt][rr] + bias + x[(size_t)row * CDIM + col];
        }
    }
}

extern "C" void kernel_launch(void* const* d_in, const int* in_sizes, int n_in,
                              void* d_out, int out_size, void* d_ws, size_t ws_size,
                              hipStream_t stream) {
    const float* pos = (const float*)d_in[0];
    const float* x   = (const float*)d_in[1];
    const int*   snd = (const int*)d_in[2];
    const int*   rcv = (const int*)d_in[3];
    const float* w1  = (const float*)d_in[4];
    const float* b1  = (const float*)d_in[5];
    const float* w2  = (const float*)d_in[6];
    const float* b2  = (const float*)d_in[7];
    const float* w3  = (const float*)d_in[8];
    const float* w4  = (const float*)d_in[9];
    const float* b4  = (const float*)d_in[10];
    const float* w5  = (const float*)d_in[11];
    const float* b5  = (const float*)d_in[12];

    float* out  = (float*)d_out;

    // ws: xw3h bf16 | Wtb bf16 4160x256 | w3p/w4p/w5p | w1p | w2p | cnt | slots
    unsigned char* ws = (unsigned char*)d_ws;
    unsigned short* xw3h = (unsigned short*)ws;
    size_t off = (size_t)NNODES * CDIM * 2;
    unsigned short* Wtb = (unsigned short*)(ws + off); off += (size_t)TROWS * CDIM * 2;
    unsigned short* w3p = (unsigned short*)(ws + off); off += 65536 * 2;
    unsigned short* w4p = (unsigned short*)(ws + off); off += 65536 * 2;
    unsigned short* w5p = (unsigned short*)(ws + off); off += 65536 * 2;
    unsigned short* w1p = (unsigned short*)(ws + off); off += 57344 * 2;
    unsigned short* w2p = (unsigned short*)(ws + off); off += 65536 * 2;
    int* cnt = (int*)(ws + off);                       off += (size_t)NNODES * 4;
    int2* slots = (int2*)(ws + off);

    packzero_kernel<<<PACKB + ZEROB, NTHR, 0, stream>>>(w3, w4, w5, w1, w2,
                                                        w3p, w4p, w5p, w1p, w2p,
                                                        (int4*)cnt);
    mega_kernel<<<TBLK2 + XW3B2 + FILLB4, NTHR, 0, stream>>>(w1p, b1, w2p, b2, Wtb,
                                                             x, w3p, xw3h,
                                                             pos, snd, rcv, cnt, slots);
    gathernode_kernel<<<GNB, NTHR, 0, stream>>>(cnt, slots, Wtb, xw3h,
                                                w4p, b4, w5p, b5, x, out);
}